// Round 10
// baseline (372.077 us; speedup 1.0000x reference)
//
#include <hip/hip_runtime.h>
#include <math.h>

// Problem constants
#define TBR  131072      // 64*2048 rows
#define OBS  512
#define H1N  400
#define H2N  300
#define CORE 302

// Geometry: BM=32 rows/block, 320 threads (5 waves), 4096 blocks, 4 blocks/CU.
// 25 N-tiles / 5 waves = exactly 5 each -> perfectly balanced, guard-free L1 loop.
#define BM     32
#define NTH    320
#define CH_K   64        // frame K-chunk
#define NCHUNK 8         // OBS / CH_K
#define CH_S   72        // chunk stride (r3-proven padding)
#define H1_S   424       // h1/core stride (K padded 400->416, head pad ->320)

typedef __bf16 bf16x8 __attribute__((ext_vector_type(8)));
typedef __bf16 bf16x4 __attribute__((ext_vector_type(4)));
typedef float  f32x4  __attribute__((ext_vector_type(4)));

__device__ __forceinline__ bf16x8 cvt8(float4 a, float4 b) {
    bf16x8 v;
    v[0] = (__bf16)a.x; v[1] = (__bf16)a.y; v[2] = (__bf16)a.z; v[3] = (__bf16)a.w;
    v[4] = (__bf16)b.x; v[5] = (__bf16)b.y; v[6] = (__bf16)b.z; v[7] = (__bf16)b.w;
    return v;
}

// ---- weight fp32 -> bf16 pre-convert ----
__global__ void conv_weights(const float* __restrict__ W1,
                             const float* __restrict__ W2,
                             __bf16* __restrict__ ws) {
    const int n1 = (H1N * OBS) / 8;     // 25600
    const int n2 = (H2N * H1N) / 8;     // 15000
    int i = blockIdx.x * blockDim.x + threadIdx.x;
    if (i < n1) {
        const float4* p = reinterpret_cast<const float4*>(W1 + (size_t)i * 8);
        *reinterpret_cast<bf16x8*>(ws + (size_t)i * 8) = cvt8(p[0], p[1]);
    } else if (i < n1 + n2) {
        int j = i - n1;
        const float4* p = reinterpret_cast<const float4*>(W2 + (size_t)j * 8);
        *reinterpret_cast<bf16x8*>(ws + (size_t)(H1N * OBS) + (size_t)j * 8) =
            cvt8(p[0], p[1]);
    }
}

template <bool WBF16>
__global__ __launch_bounds__(NTH, 5) void autoprune_mfma(
    const float* __restrict__ frame, const float* __restrict__ reward,
    const int*   __restrict__ last_action, const float* __restrict__ eps,
    const float* __restrict__ W1f, const float* __restrict__ b1,
    const float* __restrict__ W2f, const float* __restrict__ b2,
    const float* __restrict__ Wp, const float* __restrict__ bp,
    const float* __restrict__ Wb, const float* __restrict__ bb,
    const __bf16* __restrict__ W1b, const __bf16* __restrict__ W2b,
    float* __restrict__ out)
{
    __shared__ __bf16 sm_chunk[2][BM * CH_S];   // 9,216 B (frame dbuf)
    __shared__ __bf16 sm_h1[BM * H1_S];         // 27,136 B  => 36,352 total

    const int tid  = threadIdx.x;
    const int w    = tid >> 6;          // wave 0..4
    const int l15  = tid & 15;
    const int lg   = (tid & 63) >> 4;
    const int row0 = blockIdx.x * BM;

    // staging coords: 8 threads/row over 32 rows (256 stagers, waves 0..3)
    const int sr = tid >> 3;            // 0..39 (only <32 used)
    const int sc = (tid & 7) * 8;       // 0..56
    const bool stager = (tid < 256);
    const float* fbase = frame + (size_t)(row0 + (sr & 31)) * OBS + sc;

    // ---------------- Prologue: stage chunk 0; zero h1 K-pad ------------------
    {
        float4 a, b;
        if (stager) {
            a = *reinterpret_cast<const float4*>(fbase);
            b = *reinterpret_cast<const float4*>(fbase + 4);
        }
        if (tid < 96) {                  // zero h1 cols 400..423 (32 rows x 3)
            int r = tid / 3, c = 400 + (tid % 3) * 8;
            bf16x8 z;
            #pragma unroll
            for (int j = 0; j < 8; ++j) z[j] = (__bf16)0.0f;
            *reinterpret_cast<bf16x8*>(&sm_h1[r * H1_S + c]) = z;
        }
        if (stager)
            *reinterpret_cast<bf16x8*>(&sm_chunk[0][sr * CH_S + sc]) = cvt8(a, b);
    }
    __syncthreads();

    // ---------------- Layer 1: h1 = relu(frame @ W1^T + b1) -------------------
    // M=32 (2 mt), N=400: wave w owns nt = w + 5*ti, ti<5 (exact, NO guard).
    {
        f32x4 acc[5][2];
        #pragma unroll
        for (int a = 0; a < 5; ++a)
            #pragma unroll
            for (int b = 0; b < 2; ++b) acc[a][b] = (f32x4){0.f, 0.f, 0.f, 0.f};

        for (int c = 0; c < NCHUNK; ++c) {
            float4 pa, pb;
            if (stager && c < NCHUNK - 1) {   // issue next-chunk loads early
                pa = *reinterpret_cast<const float4*>(fbase + (c + 1) * CH_K);
                pb = *reinterpret_cast<const float4*>(fbase + (c + 1) * CH_K + 4);
            }
            const __bf16* buf = sm_chunk[c & 1];
            #pragma unroll
            for (int ks = 0; ks < 2; ++ks) {
                const int kl = ks * 32 + lg * 8;
                bf16x8 afr[2];
                #pragma unroll
                for (int mt = 0; mt < 2; ++mt)
                    afr[mt] = *reinterpret_cast<const bf16x8*>(
                        &buf[(mt * 16 + l15) * CH_S + kl]);
                const int kg = c * CH_K + kl;
                #pragma unroll
                for (int ti = 0; ti < 5; ++ti) {
                    const int nt = w + ti * 5;          // always < 25
                    bf16x8 bfr;
                    if constexpr (WBF16) {
                        bfr = *reinterpret_cast<const bf16x8*>(
                            W1b + (size_t)(nt * 16 + l15) * OBS + kg);
                    } else {
                        const float4* wp = reinterpret_cast<const float4*>(
                            W1f + (size_t)(nt * 16 + l15) * OBS + kg);
                        bfr = cvt8(wp[0], wp[1]);
                    }
                    #pragma unroll
                    for (int mt = 0; mt < 2; ++mt)
                        acc[ti][mt] = __builtin_amdgcn_mfma_f32_16x16x32_bf16(
                            afr[mt], bfr, acc[ti][mt], 0, 0, 0);
                }
            }
            if (stager && c < NCHUNK - 1)
                *reinterpret_cast<bf16x8*>(
                    &sm_chunk[(c + 1) & 1][sr * CH_S + sc]) = cvt8(pa, pb);
            __syncthreads();
        }

        // C-store: col = nt*16 + l15, row = mt*16 + lg*4 + j
        #pragma unroll
        for (int ti = 0; ti < 5; ++ti) {
            const int nt = w + ti * 5;
            int c = nt * 16 + l15;
            float bias = b1[c];
            #pragma unroll
            for (int mt = 0; mt < 2; ++mt)
                #pragma unroll
                for (int j = 0; j < 4; ++j) {
                    int r = mt * 16 + lg * 4 + j;
                    sm_h1[r * H1_S + c] =
                        (__bf16)fmaxf(acc[ti][mt][j] + bias, 0.0f);
                }
        }
    }
    __syncthreads();

    // ---------------- Layer 2: h2 = relu(h1 @ W2^T + b2) ----------------------
    // M=32, N=304: nt = w + 5*ti, ti<4 (guard nt<19). K=416, 13 ksteps.
    f32x4 acc2[4][2];
    #pragma unroll
    for (int a = 0; a < 4; ++a)
        #pragma unroll
        for (int b = 0; b < 2; ++b) acc2[a][b] = (f32x4){0.f, 0.f, 0.f, 0.f};

    #pragma unroll 2
    for (int ks = 0; ks < 13; ++ks) {
        const int kb = ks * 32 + lg * 8;
        bf16x8 afr[2];
        #pragma unroll
        for (int mt = 0; mt < 2; ++mt)
            afr[mt] = *reinterpret_cast<const bf16x8*>(
                &sm_h1[(mt * 16 + l15) * H1_S + kb]);
        const int kbw = (kb >= 400) ? 0 : kb;    // A is zero there; clamp B addr
        #pragma unroll
        for (int ti = 0; ti < 4; ++ti) {
            const int nt = w + ti * 5;
            if (nt < 19) {                       // wave-uniform guard
                int cc = nt * 16 + l15;
                if (cc >= 300) cc = 299;         // results discarded
                bf16x8 bfr;
                if constexpr (WBF16) {
                    bfr = *reinterpret_cast<const bf16x8*>(
                        W2b + (size_t)cc * H1N + kbw);
                } else {
                    const float4* wp = reinterpret_cast<const float4*>(
                        W2f + (size_t)cc * H1N + kbw);
                    bfr = cvt8(wp[0], wp[1]);
                }
                #pragma unroll
                for (int mt = 0; mt < 2; ++mt)
                    acc2[ti][mt] = __builtin_amdgcn_mfma_f32_16x16x32_bf16(
                        afr[mt], bfr, acc2[ti][mt], 0, 0, 0);
            }
        }
    }
    __syncthreads();   // all h1 reads done; safe to overwrite in place

    // core (in place): cols 0..299 = relu(h2), 300=cr, 301=la, 302..319=0
    #pragma unroll
    for (int ti = 0; ti < 4; ++ti) {
        const int nt = w + ti * 5;
        if (nt < 19) {
            int c = nt * 16 + l15;
            if (c < 300) {
                float bias = b2[c];
                #pragma unroll
                for (int mt = 0; mt < 2; ++mt)
                    #pragma unroll
                    for (int j = 0; j < 4; ++j) {
                        int r = mt * 16 + lg * 4 + j;
                        sm_h1[r * H1_S + c] =
                            (__bf16)fmaxf(acc2[ti][mt][j] + bias, 0.0f);
                    }
            }
        }
    }
    if (tid < BM) {
        int r = row0 + tid;
        float cr = fminf(fmaxf(reward[r], -1.0f), 1.0f);
        bf16x4 tail;
        tail[0] = (__bf16)cr;
        tail[1] = (__bf16)(float)last_action[r];
        tail[2] = (__bf16)0.0f;
        tail[3] = (__bf16)0.0f;
        *reinterpret_cast<bf16x4*>(&sm_h1[tid * H1_S + 300]) = tail;
        bf16x8 z;
        #pragma unroll
        for (int j = 0; j < 8; ++j) z[j] = (__bf16)0.0f;
        *reinterpret_cast<bf16x8*>(&sm_h1[tid * H1_S + 304]) = z;
        *reinterpret_cast<bf16x8*>(&sm_h1[tid * H1_S + 312]) = z;
    }
    __syncthreads();

    // ---------------- Head: MFMA with register-built B ------------------------
    // waves 0..1 handle 16 rows each; lane l15 = output o (0:mu, 1:sigma, 2:bl)
    if (w < 2) {
        f32x4 hac = (f32x4){0.f, 0.f, 0.f, 0.f};
        const float* wsrc = (l15 == 2) ? Wb : (Wp + l15 * CORE);  // l15>2 unused
        #pragma unroll
        for (int ks = 0; ks < 10; ++ks) {
            int kb = ks * 32 + lg * 8;
            bf16x8 afr = *reinterpret_cast<const bf16x8*>(
                &sm_h1[(w * 16 + l15) * H1_S + kb]);
            bf16x8 bfr;
            #pragma unroll
            for (int e = 0; e < 8; ++e) {
                int k = kb + e;
                bfr[e] = (l15 < 3 && k < CORE) ? (__bf16)wsrc[k] : (__bf16)0.0f;
            }
            hac = __builtin_amdgcn_mfma_f32_16x16x32_bf16(afr, bfr, hac, 0, 0, 0);
        }
        float bias = (l15 == 0) ? bp[0] : (l15 == 1) ? bp[1] : (l15 == 2) ? bb[0] : 0.0f;
        #pragma unroll
        for (int j = 0; j < 4; ++j) {
            float v = hac[j] + bias;
            if (l15 < 2) v = 1.0f / (1.0f + __expf(-v));
            float ot = __shfl_xor(v, 1);       // lane l15=0 receives sigma
            int r = row0 + w * 16 + lg * 4 + j;
            if (l15 == 0) {
                out[(size_t)r * 4 + 0] = v;                     // mu
                out[(size_t)r * 4 + 3] = fmaf(ot, eps[r], v);   // action
            } else if (l15 == 1) {
                out[(size_t)r * 4 + 1] = v;                     // sigma
            } else if (l15 == 2) {
                out[(size_t)r * 4 + 2] = v;                     // baseline
            }
        }
    }
}

extern "C" void kernel_launch(void* const* d_in, const int* in_sizes, int n_in,
                              void* d_out, int out_size, void* d_ws, size_t ws_size,
                              hipStream_t stream) {
    const float* frame       = (const float*)d_in[0];
    const float* reward      = (const float*)d_in[1];
    const int*   last_action = (const int*)  d_in[2];
    const float* eps         = (const float*)d_in[3];
    const float* W1          = (const float*)d_in[4];
    const float* b1          = (const float*)d_in[5];
    const float* W2          = (const float*)d_in[6];
    const float* b2          = (const float*)d_in[7];
    const float* Wp          = (const float*)d_in[8];
    const float* bp          = (const float*)d_in[9];
    const float* Wb          = (const float*)d_in[10];
    const float* bb          = (const float*)d_in[11];
    float* out = (float*)d_out;

    const size_t wbytes = (size_t)(H1N * OBS + H2N * H1N) * 2;   // 649600
    dim3 grid(TBR / BM);   // 4096 blocks, 320 threads, 4 blocks/CU (36.4 KB LDS)

    if (ws_size >= wbytes) {
        __bf16* wsb = (__bf16*)d_ws;
        int nconv = (H1N * OBS + H2N * H1N) / 8;                 // 40600
        conv_weights<<<(nconv + 255) / 256, 256, 0, stream>>>(W1, W2, wsb);
        autoprune_mfma<true><<<grid, NTH, 0, stream>>>(
            frame, reward, last_action, eps, W1, b1, W2, b2, Wp, bp, Wb, bb,
            (const __bf16*)wsb, (const __bf16*)(wsb + H1N * OBS), out);
    } else {
        autoprune_mfma<false><<<grid, NTH, 0, stream>>>(
            frame, reward, last_action, eps, W1, b1, W2, b2, Wp, bp, Wb, bb,
            (const __bf16*)nullptr, (const __bf16*)nullptr, out);
    }
}

// Round 11
// 218.568 us; speedup vs baseline: 1.7023x; 1.7023x over previous
//
#include <hip/hip_runtime.h>
#include <math.h>

// Problem constants
#define TBR  131072      // 64*2048 rows
#define OBS  512
#define H1N  400
#define H2N  300
#define CORE 302

// Geometry (r3 champion): 64 rows/block, 512 threads, 2 blocks/CU.
#define CH_K   64        // frame K-chunk
#define NCHUNK 8         // OBS / CH_K
#define CH_S   64        // chunk stride, exact; T2 XOR-swizzled (r8: 0 conflicts)
#define H1_S   424       // h1/core stride (K padded 400->416, head pad ->320)

typedef __bf16 bf16x8 __attribute__((ext_vector_type(8)));
typedef __bf16 bf16x4 __attribute__((ext_vector_type(4)));
typedef float  f32x4  __attribute__((ext_vector_type(4)));

__device__ __forceinline__ bf16x8 cvt8(float4 a, float4 b) {
    bf16x8 v;
    v[0] = (__bf16)a.x; v[1] = (__bf16)a.y; v[2] = (__bf16)a.z; v[3] = (__bf16)a.w;
    v[4] = (__bf16)b.x; v[5] = (__bf16)b.y; v[6] = (__bf16)b.z; v[7] = (__bf16)b.w;
    return v;
}

// chunk-buffer address, T2 XOR swizzle on 16B slots (write & read same map)
__device__ __forceinline__ int chadr(int r, int c8) {
    return r * CH_S + (c8 ^ ((r & 7) << 3));
}

// ---- weight fp32 -> bf16 pre-convert ----
__global__ void conv_weights(const float* __restrict__ W1,
                             const float* __restrict__ W2,
                             __bf16* __restrict__ ws) {
    const int n1 = (H1N * OBS) / 8;     // 25600
    const int n2 = (H2N * H1N) / 8;     // 15000
    int i = blockIdx.x * blockDim.x + threadIdx.x;
    if (i < n1) {
        const float4* p = reinterpret_cast<const float4*>(W1 + (size_t)i * 8);
        *reinterpret_cast<bf16x8*>(ws + (size_t)i * 8) = cvt8(p[0], p[1]);
    } else if (i < n1 + n2) {
        int j = i - n1;
        const float4* p = reinterpret_cast<const float4*>(W2 + (size_t)j * 8);
        *reinterpret_cast<bf16x8*>(ws + (size_t)(H1N * OBS) + (size_t)j * 8) =
            cvt8(p[0], p[1]);
    }
}

template <bool WBF16>
__global__ __launch_bounds__(512, 4) void autoprune_mfma(
    const float* __restrict__ frame, const float* __restrict__ reward,
    const int*   __restrict__ last_action, const float* __restrict__ eps,
    const float* __restrict__ W1f, const float* __restrict__ b1,
    const float* __restrict__ W2f, const float* __restrict__ b2,
    const float* __restrict__ Wp, const float* __restrict__ bp,
    const float* __restrict__ Wb, const float* __restrict__ bb,
    const __bf16* __restrict__ W1b, const __bf16* __restrict__ W2b,
    float* __restrict__ out)
{
    __shared__ __bf16 sm_chunk[3][64 * CH_S];   // 24,576 B (3-deep, swizzled)
    __shared__ __bf16 sm_h1[64 * H1_S];         // 54,272 B  => 78,848 total

    const int tid  = threadIdx.x;
    const int w    = tid >> 6;
    const int l15  = tid & 15;
    const int lg   = (tid & 63) >> 4;
    const int row0 = blockIdx.x * 64;

    // staging coords: 8 threads/row
    const int sr = tid >> 3;            // 0..63
    const int sc = (tid & 7) * 8;       // 0..56
    const float* fbase = frame + (size_t)(row0 + sr) * OBS + sc;

    // ---------------- Prologue: issue c0,c1; write c0; zero h1 pad ------------
    float4 st[2][2];                    // statically indexed after full unroll
    st[0][0] = *reinterpret_cast<const float4*>(fbase);
    st[0][1] = *reinterpret_cast<const float4*>(fbase + 4);
    st[1][0] = *reinterpret_cast<const float4*>(fbase + CH_K);
    st[1][1] = *reinterpret_cast<const float4*>(fbase + CH_K + 4);
    if (tid < 192) {                    // zero h1 cols 400..423
        int r = tid / 3, c = 400 + (tid % 3) * 8;
        bf16x8 z;
        #pragma unroll
        for (int j = 0; j < 8; ++j) z[j] = (__bf16)0.0f;
        *reinterpret_cast<bf16x8*>(&sm_h1[r * H1_S + c]) = z;
    }
    *reinterpret_cast<bf16x8*>(&sm_chunk[0][chadr(sr, sc)]) =
        cvt8(st[0][0], st[0][1]);
    __syncthreads();

    // ---------------- Layer 1: h1 = relu(frame @ W1^T + b1) -------------------
    // M=64 (4 mt), N=400 (25 nt over 8 waves), K=512 = 8 chunks x 2 ksteps.
    // 3-deep frame pipeline: iter c issues loads c+2, ds_writes c+1 (loaded one
    // period ago), raw lgkm-barrier (c+2 loads stay in flight), computes c.
    {
        f32x4 acc[4][4];
        #pragma unroll
        for (int a = 0; a < 4; ++a)
            #pragma unroll
            for (int b = 0; b < 4; ++b) acc[a][b] = (f32x4){0.f, 0.f, 0.f, 0.f};

        #pragma unroll
        for (int c = 0; c < NCHUNK; ++c) {
            if (c + 2 < NCHUNK) {       // issue chunk c+2 (2 periods ahead)
                st[c & 1][0] = *reinterpret_cast<const float4*>(
                    fbase + (c + 2) * CH_K);
                st[c & 1][1] = *reinterpret_cast<const float4*>(
                    fbase + (c + 2) * CH_K + 4);
            }
            if (c + 1 < NCHUNK) {       // write chunk c+1 (landed last period)
                *reinterpret_cast<bf16x8*>(
                    &sm_chunk[(c + 1) % 3][chadr(sr, sc)]) =
                    cvt8(st[(c + 1) & 1][0], st[(c + 1) & 1][1]);
            }
            asm volatile("s_waitcnt lgkmcnt(0)" ::: "memory");
            __builtin_amdgcn_s_barrier();   // vmem (c+2 frame loads) NOT drained

            const __bf16* buf = sm_chunk[c % 3];
            #pragma unroll
            for (int ks = 0; ks < 2; ++ks) {
                const int kl = ks * 32 + lg * 8;
                bf16x8 afr[4];
                #pragma unroll
                for (int mt = 0; mt < 4; ++mt)
                    afr[mt] = *reinterpret_cast<const bf16x8*>(
                        &buf[chadr(mt * 16 + l15, kl)]);
                const int kg = c * CH_K + kl;
                #pragma unroll
                for (int ti = 0; ti < 4; ++ti) {
                    int nt = w + ti * 8;
                    if (nt < 25) {      // wave-uniform guard
                        bf16x8 bfr;
                        if constexpr (WBF16) {
                            bfr = *reinterpret_cast<const bf16x8*>(
                                W1b + (size_t)(nt * 16 + l15) * OBS + kg);
                        } else {
                            const float4* wp = reinterpret_cast<const float4*>(
                                W1f + (size_t)(nt * 16 + l15) * OBS + kg);
                            bfr = cvt8(wp[0], wp[1]);
                        }
                        #pragma unroll
                        for (int mt = 0; mt < 4; ++mt)
                            acc[ti][mt] = __builtin_amdgcn_mfma_f32_16x16x32_bf16(
                                afr[mt], bfr, acc[ti][mt], 0, 0, 0);
                    }
                }
            }
        }

        // C-store: col = nt*16 + l15, row = mt*16 + lg*4 + j
        __syncthreads();   // all chunk reads done before any h1 write ordering issues
        #pragma unroll
        for (int ti = 0; ti < 4; ++ti) {
            int nt = w + ti * 8;
            if (nt < 25) {
                int c = nt * 16 + l15;
                float bias = b1[c];
                #pragma unroll
                for (int mt = 0; mt < 4; ++mt)
                    #pragma unroll
                    for (int j = 0; j < 4; ++j) {
                        int r = mt * 16 + lg * 4 + j;
                        sm_h1[r * H1_S + c] =
                            (__bf16)fmaxf(acc[ti][mt][j] + bias, 0.0f);
                    }
            }
        }
    }
    __syncthreads();

    // ---------------- Layer 2: h2 = relu(h1 @ W2^T + b2) ----------------------
    // M=64, N=304 (19 nt), K=416 (13 ksteps, no barriers; A zero-padded)
    f32x4 acc2[3][4];
    #pragma unroll
    for (int a = 0; a < 3; ++a)
        #pragma unroll
        for (int b = 0; b < 4; ++b) acc2[a][b] = (f32x4){0.f, 0.f, 0.f, 0.f};

    #pragma unroll 2
    for (int ks = 0; ks < 13; ++ks) {
        const int kb = ks * 32 + lg * 8;
        bf16x8 afr[4];
        #pragma unroll
        for (int mt = 0; mt < 4; ++mt)
            afr[mt] = *reinterpret_cast<const bf16x8*>(
                &sm_h1[(mt * 16 + l15) * H1_S + kb]);
        const int kbw = (kb >= 400) ? 0 : kb;    // A is zero there; clamp B addr
        #pragma unroll
        for (int ti = 0; ti < 3; ++ti) {
            int nt = w + ti * 8;
            if (nt < 19) {
                int cc = nt * 16 + l15;
                if (cc >= 300) cc = 299;         // results discarded
                bf16x8 bfr;
                if constexpr (WBF16) {
                    bfr = *reinterpret_cast<const bf16x8*>(
                        W2b + (size_t)cc * H1N + kbw);
                } else {
                    const float4* wp = reinterpret_cast<const float4*>(
                        W2f + (size_t)cc * H1N + kbw);
                    bfr = cvt8(wp[0], wp[1]);
                }
                #pragma unroll
                for (int mt = 0; mt < 4; ++mt)
                    acc2[ti][mt] = __builtin_amdgcn_mfma_f32_16x16x32_bf16(
                        afr[mt], bfr, acc2[ti][mt], 0, 0, 0);
            }
        }
    }
    __syncthreads();   // all h1 reads done; safe to overwrite in place

    // core (in place): cols 0..299 = relu(h2), 300=cr, 301=la, 302..319=0
    #pragma unroll
    for (int ti = 0; ti < 3; ++ti) {
        int nt = w + ti * 8;
        if (nt < 19) {
            int c = nt * 16 + l15;
            if (c < 300) {
                float bias = b2[c];
                #pragma unroll
                for (int mt = 0; mt < 4; ++mt)
                    #pragma unroll
                    for (int j = 0; j < 4; ++j) {
                        int r = mt * 16 + lg * 4 + j;
                        sm_h1[r * H1_S + c] =
                            (__bf16)fmaxf(acc2[ti][mt][j] + bias, 0.0f);
                    }
            }
        }
    }
    if (tid < 64) {
        int r = row0 + tid;
        float cr = fminf(fmaxf(reward[r], -1.0f), 1.0f);
        bf16x4 tail;
        tail[0] = (__bf16)cr;
        tail[1] = (__bf16)(float)last_action[r];
        tail[2] = (__bf16)0.0f;
        tail[3] = (__bf16)0.0f;
        *reinterpret_cast<bf16x4*>(&sm_h1[tid * H1_S + 300]) = tail;
        bf16x8 z;
        #pragma unroll
        for (int j = 0; j < 8; ++j) z[j] = (__bf16)0.0f;
        *reinterpret_cast<bf16x8*>(&sm_h1[tid * H1_S + 304]) = z;
        *reinterpret_cast<bf16x8*>(&sm_h1[tid * H1_S + 312]) = z;
    }
    __syncthreads();

    // ---------------- Head: MFMA with register-built B ------------------------
    // waves 0..3 handle 16 rows each; lane l15 = output o (0:mu, 1:sigma, 2:bl)
    if (w < 4) {
        f32x4 hac = (f32x4){0.f, 0.f, 0.f, 0.f};
        const float* wsrc = (l15 == 2) ? Wb : (Wp + l15 * CORE);  // l15>2 unused
        #pragma unroll
        for (int ks = 0; ks < 10; ++ks) {
            int kb = ks * 32 + lg * 8;
            bf16x8 afr = *reinterpret_cast<const bf16x8*>(
                &sm_h1[(w * 16 + l15) * H1_S + kb]);
            bf16x8 bfr;
            #pragma unroll
            for (int e = 0; e < 8; ++e) {
                int k = kb + e;
                bfr[e] = (l15 < 3 && k < CORE) ? (__bf16)wsrc[k] : (__bf16)0.0f;
            }
            hac = __builtin_amdgcn_mfma_f32_16x16x32_bf16(afr, bfr, hac, 0, 0, 0);
        }
        float bias = (l15 == 0) ? bp[0] : (l15 == 1) ? bp[1] : (l15 == 2) ? bb[0] : 0.0f;
        #pragma unroll
        for (int j = 0; j < 4; ++j) {
            float v = hac[j] + bias;
            if (l15 < 2) v = 1.0f / (1.0f + __expf(-v));
            float ot = __shfl_xor(v, 1);       // lane l15=0 receives sigma
            int r = row0 + w * 16 + lg * 4 + j;
            if (l15 == 0) {
                out[(size_t)r * 4 + 0] = v;                     // mu
                out[(size_t)r * 4 + 3] = fmaf(ot, eps[r], v);   // action
            } else if (l15 == 1) {
                out[(size_t)r * 4 + 1] = v;                     // sigma
            } else if (l15 == 2) {
                out[(size_t)r * 4 + 2] = v;                     // baseline
            }
        }
    }
}

extern "C" void kernel_launch(void* const* d_in, const int* in_sizes, int n_in,
                              void* d_out, int out_size, void* d_ws, size_t ws_size,
                              hipStream_t stream) {
    const float* frame       = (const float*)d_in[0];
    const float* reward      = (const float*)d_in[1];
    const int*   last_action = (const int*)  d_in[2];
    const float* eps         = (const float*)d_in[3];
    const float* W1          = (const float*)d_in[4];
    const float* b1          = (const float*)d_in[5];
    const float* W2          = (const float*)d_in[6];
    const float* b2          = (const float*)d_in[7];
    const float* Wp          = (const float*)d_in[8];
    const float* bp          = (const float*)d_in[9];
    const float* Wb          = (const float*)d_in[10];
    const float* bb          = (const float*)d_in[11];
    float* out = (float*)d_out;

    const size_t wbytes = (size_t)(H1N * OBS + H2N * H1N) * 2;   // 649600
    dim3 grid(TBR / 64);   // 2048 blocks, 512 threads, 2 blocks/CU (78.8 KB LDS)

    if (ws_size >= wbytes) {
        __bf16* wsb = (__bf16*)d_ws;
        int nconv = (H1N * OBS + H2N * H1N) / 8;                 // 40600
        conv_weights<<<(nconv + 255) / 256, 256, 0, stream>>>(W1, W2, wsb);
        autoprune_mfma<true><<<grid, 512, 0, stream>>>(
            frame, reward, last_action, eps, W1, b1, W2, b2, Wp, bp, Wb, bb,
            (const __bf16*)wsb, (const __bf16*)(wsb + H1N * OBS), out);
    } else {
        autoprune_mfma<false><<<grid, 512, 0, stream>>>(
            frame, reward, last_action, eps, W1, b1, W2, b2, Wp, bp, Wb, bb,
            (const __bf16*)nullptr, (const __bf16*)nullptr, out);
    }
}